// Round 3
// baseline (921.334 us; speedup 1.0000x reference)
//
#include <hip/hip_runtime.h>
#include <hip/hip_bf16.h>

#define N_NODES 50000
#define N_EDGES 800000
#define EN_EDGES (N_EDGES + N_NODES)   // with self-loops
#define IN_F 128
#define H_F 64
#define BN_EPS 1e-5f
#define SCAN_NB 49                     // ceil(50000/1024)

// ---------------- CSR build ----------------

__global__ void k_init(int* __restrict__ cursor, float* __restrict__ pool) {
    int i = blockIdx.x * 256 + threadIdx.x;
    if (i < N_NODES) cursor[i] = 1;        // self-loop pre-count
    if (i < H_F) pool[i] = 0.f;
}

__global__ void k_hist(const int* __restrict__ dst, int* __restrict__ cursor) {
    int e = blockIdx.x * 256 + threadIdx.x;
    if (e < N_EDGES) atomicAdd(&cursor[dst[e]], 1);
}

__global__ void k_scan_bsum(const int* __restrict__ cnt, int* __restrict__ bsum) {
    __shared__ int sd[256];
    int b = blockIdx.x, t = threadIdx.x;
    int base = b * 1024;
    int s = 0;
    for (int i = t; i < 1024; i += 256) {
        int idx = base + i;
        if (idx < N_NODES) s += cnt[idx];
    }
    sd[t] = s; __syncthreads();
    for (int d = 128; d > 0; d >>= 1) {
        if (t < d) sd[t] += sd[t + d];
        __syncthreads();
    }
    if (t == 0) bsum[b] = sd[0];
}

__global__ void k_scan_small(int* __restrict__ bsum, int* __restrict__ offsets) {
    if (threadIdx.x == 0 && blockIdx.x == 0) {
        int run = 0;
        for (int i = 0; i < SCAN_NB; i++) { int v = bsum[i]; bsum[i] = run; run += v; }
        offsets[N_NODES] = run;
    }
}

// cntcur is read as counts, overwritten with start offsets (same index per thread -> safe)
__global__ void k_scan_final(int* __restrict__ cntcur, const int* __restrict__ bsum,
                             int* __restrict__ offsets) {
    __shared__ int ls[256];
    int b = blockIdx.x, t = threadIdx.x;
    int i0 = b * 1024 + t * 4;
    int c0 = 0, c1 = 0, c2 = 0, c3 = 0;
    if (i0 + 0 < N_NODES) c0 = cntcur[i0 + 0];
    if (i0 + 1 < N_NODES) c1 = cntcur[i0 + 1];
    if (i0 + 2 < N_NODES) c2 = cntcur[i0 + 2];
    if (i0 + 3 < N_NODES) c3 = cntcur[i0 + 3];
    int tsum = c0 + c1 + c2 + c3;
    ls[t] = tsum; __syncthreads();
    for (int d = 1; d < 256; d <<= 1) {
        int v = (t >= d) ? ls[t - d] : 0;
        __syncthreads();
        ls[t] += v;
        __syncthreads();
    }
    int tex = ls[t] - tsum;               // exclusive prefix within block
    int base = bsum[b] + tex;
    if (i0 + 0 < N_NODES) { offsets[i0 + 0] = base; cntcur[i0 + 0] = base; base += c0; }
    if (i0 + 1 < N_NODES) { offsets[i0 + 1] = base; cntcur[i0 + 1] = base; base += c1; }
    if (i0 + 2 < N_NODES) { offsets[i0 + 2] = base; cntcur[i0 + 2] = base; base += c2; }
    if (i0 + 3 < N_NODES) { offsets[i0 + 3] = base; cntcur[i0 + 3] = base; base += c3; }
}

__global__ void k_scatter(const int* __restrict__ src, const int* __restrict__ dst,
                          int* __restrict__ cursor, int* __restrict__ ssrc) {
    int e = blockIdx.x * 256 + threadIdx.x;
    if (e >= EN_EDGES) return;
    int s, d;
    if (e < N_EDGES) { s = src[e]; d = dst[e]; }
    else { s = e - N_EDGES; d = s; }
    int pos = atomicAdd(&cursor[d], 1);
    ssrc[pos] = s;
}

// ---------------- Layer 1 GEMM (K=128, fp32 inputs) ----------------
// h = x @ W ; asn = h . a_s ; adn = h . a_d
__global__ __launch_bounds__(256) void k_gemm1(
        const float* __restrict__ x, const float* __restrict__ W,
        const float* __restrict__ a_s, const float* __restrict__ a_d,
        float* __restrict__ h, float* __restrict__ asn, float* __restrict__ adn) {
    __shared__ float Wl[IN_F][H_F];
    int t = threadIdx.x;
    int lane = t & 63, wave = t >> 6;
    for (int i = t; i < IN_F * H_F; i += 256) Wl[i >> 6][i & 63] = W[i];
    float as_l = a_s[lane];
    float ad_l = a_d[lane];
    __syncthreads();
    int row0 = blockIdx.x * 32 + wave * 8;
    for (int row = row0; row < row0 + 8 && row < N_NODES; row++) {
        float x0 = x[row * IN_F + lane];
        float x1 = x[row * IN_F + 64 + lane];
        float acc = 0.f;
        #pragma unroll
        for (int k = 0; k < 64; k++) acc += __shfl(x0, k) * Wl[k][lane];
        #pragma unroll
        for (int k = 0; k < 64; k++) acc += __shfl(x1, k) * Wl[64 + k][lane];
        h[row * H_F + lane] = acc;
        float va = acc * as_l, vb = acc * ad_l;
        #pragma unroll
        for (int d = 32; d > 0; d >>= 1) { va += __shfl_xor(va, d); vb += __shfl_xor(vb, d); }
        if (lane == 0) { asn[row] = va; adn[row] = vb; }
    }
}

// ---------------- Layers 2-5 GEMM (K=64, fp32 activations) ----------------
// h = xp @ W ; p = xp @ PW + pb ; asn/adn dots
__global__ __launch_bounds__(256) void k_gemm(
        const float* __restrict__ xp, const float* __restrict__ W,
        const float* __restrict__ PW, const float* __restrict__ pb,
        const float* __restrict__ a_s, const float* __restrict__ a_d,
        float* __restrict__ h, float* __restrict__ p,
        float* __restrict__ asn, float* __restrict__ adn) {
    __shared__ float Wl[H_F][H_F];
    __shared__ float Pl[H_F][H_F];
    int t = threadIdx.x;
    int lane = t & 63, wave = t >> 6;
    for (int i = t; i < H_F * H_F; i += 256) {
        Wl[i >> 6][i & 63] = W[i];
        Pl[i >> 6][i & 63] = PW[i];
    }
    float as_l = a_s[lane];
    float ad_l = a_d[lane];
    float pb_l = pb[lane];
    __syncthreads();
    int row0 = blockIdx.x * 32 + wave * 8;
    for (int row = row0; row < row0 + 8 && row < N_NODES; row++) {
        float xv = xp[row * H_F + lane];
        float acc = 0.f, pacc = pb_l;
        #pragma unroll
        for (int k = 0; k < 64; k++) {
            float xk = __shfl(xv, k);
            acc += xk * Wl[k][lane];
            pacc += xk * Pl[k][lane];
        }
        h[row * H_F + lane] = acc;
        p[row * H_F + lane] = pacc;
        float va = acc * as_l, vb = acc * ad_l;
        #pragma unroll
        for (int d = 32; d > 0; d >>= 1) { va += __shfl_xor(va, d); vb += __shfl_xor(vb, d); }
        if (lane == 0) { asn[row] = va; adn[row] = vb; }
    }
}

// ---------------- Attention aggregation: one wave per destination ----------------
template <bool HAS_RES>
__global__ __launch_bounds__(256) void k_aggr(
        const float* __restrict__ h, const float* __restrict__ asn, const float* __restrict__ adn,
        const int* __restrict__ offsets, const int* __restrict__ ssrc,
        const float* __restrict__ bias,
        const float* __restrict__ bg, const float* __restrict__ bb,
        const float* __restrict__ bm, const float* __restrict__ bv,
        const float* __restrict__ res, float* __restrict__ out) {
    int t = threadIdx.x;
    int lane = t & 63, wave = t >> 6;
    int d = blockIdx.x * 4 + wave;
    if (d >= N_NODES) return;
    int beg = offsets[d], end = offsets[d + 1];
    float add = adn[d];

    // pass 1: online softmax (strided over lanes), then wave combine
    float m = -1e30f, ssum = 0.f;
    for (int j = beg + lane; j < end; j += 64) {
        int s = ssrc[j];
        float e = asn[s] + add;
        e = e < 0.f ? 0.2f * e : e;
        float nm = fmaxf(m, e);
        ssum = ssum * __expf(m - nm) + __expf(e - nm);
        m = nm;
    }
    #pragma unroll
    for (int dlt = 32; dlt > 0; dlt >>= 1) {
        float m2 = __shfl_xor(m, dlt);
        float s2 = __shfl_xor(ssum, dlt);
        float nm = fmaxf(m, m2);
        ssum = ssum * __expf(m - nm) + s2 * __expf(m2 - nm);
        m = nm;
    }
    float inv = 1.f / ssum;   // every dst has a self-loop -> ssum > 0

    // pass 2: weighted gather; lane l owns feature l
    float acc = 0.f;
    for (int base = beg; base < end; base += 64) {
        int cnt = min(64, end - base);
        float alpha = 0.f; int si = 0;
        if (lane < cnt) {
            si = ssrc[base + lane];
            float e = asn[si] + add;
            e = e < 0.f ? 0.2f * e : e;
            alpha = __expf(e - m) * inv;
        }
        for (int j = 0; j < cnt; j++) {
            float a = __shfl(alpha, j);
            int s = __shfl(si, j);
            acc += a * h[s * H_F + lane];
        }
    }

    // epilogue: bias -> relu -> BN -> (+ residual)
    float v = acc + bias[lane];
    v = fmaxf(v, 0.f);
    v = (v - bm[lane]) * rsqrtf(bv[lane] + BN_EPS) * bg[lane] + bb[lane];
    if (HAS_RES) v += res[d * H_F + lane];
    out[d * H_F + lane] = v;
}

// ---------------- Mean pool + head ----------------

__global__ __launch_bounds__(256) void k_pool(const float* __restrict__ x, float* __restrict__ pool) {
    __shared__ float sd[256];
    int t = threadIdx.x;
    int lane = t & 63, wave = t >> 6;
    float s = 0.f;
    for (int r = blockIdx.x * 4 + wave; r < N_NODES; r += gridDim.x * 4)
        s += x[r * H_F + lane];
    sd[t] = s; __syncthreads();
    if (wave == 0) {
        float v = sd[lane] + sd[64 + lane] + sd[128 + lane] + sd[192 + lane];
        atomicAdd(&pool[lane], v);
    }
}

__global__ void k_head(const float* __restrict__ pool,
                       const float* __restrict__ hW1, const float* __restrict__ hb1,
                       const float* __restrict__ hg, const float* __restrict__ hb,
                       const float* __restrict__ hm, const float* __restrict__ hv,
                       const float* __restrict__ hW2, const float* __restrict__ hb2,
                       float* __restrict__ out) {
    __shared__ float gl[64];
    __shared__ float h1[32];
    int t = threadIdx.x;
    if (t < 64) gl[t] = pool[t] * (1.f / N_NODES);
    __syncthreads();
    if (t < 32) {
        float s = hb1[t];
        for (int l = 0; l < 64; l++) s += gl[l] * hW1[l * 32 + t];
        s = fmaxf(s, 0.f);
        s = (s - hm[t]) * rsqrtf(hv[t] + BN_EPS) * hg[t] + hb[t];
        h1[t] = s;
    }
    __syncthreads();
    if (t == 0) {
        float s = hb2[0];
        for (int j = 0; j < 32; j++) s += h1[j] * hW2[j];
        out[0] = s;
    }
}

// ---------------- Launch ----------------

extern "C" void kernel_launch(void* const* d_in, const int* in_sizes, int n_in,
                              void* d_out, int out_size, void* d_ws, size_t ws_size,
                              hipStream_t stream) {
    (void)in_sizes; (void)n_in; (void)out_size; (void)ws_size;
    const float* x        = (const float*)d_in[0];
    const int*   ei       = (const int*)d_in[1];
    const float* conv1_W  = (const float*)d_in[2];
    const float* conv1_as = (const float*)d_in[3];
    const float* conv1_ad = (const float*)d_in[4];
    const float* conv1_b  = (const float*)d_in[5];
    const float* convW    = (const float*)d_in[6];
    const float* conv_as  = (const float*)d_in[7];
    const float* conv_ad  = (const float*)d_in[8];
    const float* conv_b   = (const float*)d_in[9];
    const float* bn_g     = (const float*)d_in[10];
    const float* bn_b     = (const float*)d_in[11];
    const float* bn_m     = (const float*)d_in[12];
    const float* bn_v     = (const float*)d_in[13];
    const float* projW    = (const float*)d_in[14];
    const float* projb    = (const float*)d_in[15];
    const float* hW1      = (const float*)d_in[16];
    const float* hb1      = (const float*)d_in[17];
    const float* hbn_g    = (const float*)d_in[18];
    const float* hbn_b    = (const float*)d_in[19];
    const float* hbn_m    = (const float*)d_in[20];
    const float* hbn_v    = (const float*)d_in[21];
    const float* hW2      = (const float*)d_in[22];
    const float* hb2      = (const float*)d_in[23];

    const int* e_src = ei;
    const int* e_dst = ei + N_EDGES;

    char* wsb = (char*)d_ws;
    size_t cur = 0;
    auto alloc = [&](size_t bytes) -> void* {
        void* p = wsb + cur;
        cur = (cur + bytes + 255) & ~(size_t)255;
        return p;
    };
    int*   offsets = (int*)alloc((N_NODES + 1) * sizeof(int));
    int*   cursor  = (int*)alloc(N_NODES * sizeof(int));
    int*   ssrc    = (int*)alloc(EN_EDGES * sizeof(int));
    int*   bsum    = (int*)alloc(64 * sizeof(int));
    float* h       = (float*)alloc((size_t)N_NODES * H_F * sizeof(float));
    float* p       = (float*)alloc((size_t)N_NODES * H_F * sizeof(float));
    float* asn     = (float*)alloc(N_NODES * sizeof(float));
    float* adn     = (float*)alloc(N_NODES * sizeof(float));
    float* xa      = (float*)alloc((size_t)N_NODES * H_F * sizeof(float));
    float* xb      = (float*)alloc((size_t)N_NODES * H_F * sizeof(float));
    float* pool    = (float*)alloc(64 * sizeof(float));

    // CSR build (graph identical for all layers)
    k_init<<<dim3((N_NODES + 255) / 256), dim3(256), 0, stream>>>(cursor, pool);
    k_hist<<<dim3((N_EDGES + 255) / 256), dim3(256), 0, stream>>>(e_dst, cursor);
    k_scan_bsum<<<dim3(SCAN_NB), dim3(256), 0, stream>>>(cursor, bsum);
    k_scan_small<<<dim3(1), dim3(64), 0, stream>>>(bsum, offsets);
    k_scan_final<<<dim3(SCAN_NB), dim3(256), 0, stream>>>(cursor, bsum, offsets);
    k_scatter<<<dim3((EN_EDGES + 255) / 256), dim3(256), 0, stream>>>(e_src, e_dst, cursor, ssrc);

    dim3 gemm_grid((N_NODES + 31) / 32), blk(256);
    dim3 aggr_grid((N_NODES + 3) / 4);

    // Layer 1
    k_gemm1<<<gemm_grid, blk, 0, stream>>>(x, conv1_W, conv1_as, conv1_ad, h, asn, adn);
    k_aggr<false><<<aggr_grid, blk, 0, stream>>>(h, asn, adn, offsets, ssrc, conv1_b,
                                                 bn_g, bn_b, bn_m, bn_v, nullptr, xa);

    // Layers 2-5
    float* bufs[2] = { xa, xb };
    for (int l = 0; l < 4; l++) {
        float* in  = bufs[l & 1];
        float* out = bufs[(l + 1) & 1];
        k_gemm<<<gemm_grid, blk, 0, stream>>>(in, convW + (size_t)l * H_F * H_F,
                                              projW + (size_t)l * H_F * H_F, projb + l * H_F,
                                              conv_as + l * H_F, conv_ad + l * H_F,
                                              h, p, asn, adn);
        k_aggr<true><<<aggr_grid, blk, 0, stream>>>(h, asn, adn, offsets, ssrc,
                                                    conv_b + l * H_F,
                                                    bn_g + (l + 1) * H_F, bn_b + (l + 1) * H_F,
                                                    bn_m + (l + 1) * H_F, bn_v + (l + 1) * H_F,
                                                    p, out);
    }

    // Pool + head (after 4 residual layers the final activations are in xa)
    k_pool<<<dim3(64), blk, 0, stream>>>(xa, pool);
    k_head<<<dim3(1), dim3(64), 0, stream>>>(pool, hW1, hb1, hbn_g, hbn_b, hbn_m, hbn_v,
                                             hW2, hb2, (float*)d_out);
}

// Round 4
// 649.784 us; speedup vs baseline: 1.4179x; 1.4179x over previous
//
#include <hip/hip_runtime.h>
#include <hip/hip_bf16.h>

#define N_NODES 50000
#define N_EDGES 800000
#define EN_EDGES (N_EDGES + N_NODES)   // with self-loops
#define IN_F 128
#define H_F 64
#define BN_EPS 1e-5f
#define SCAN_NB 49                     // ceil(50000/1024)

// ---------------- CSR build ----------------

__global__ void k_init(int* __restrict__ cursor, float* __restrict__ pool) {
    int i = blockIdx.x * 256 + threadIdx.x;
    if (i < N_NODES) cursor[i] = 1;        // self-loop pre-count
    if (i < H_F) pool[i] = 0.f;
}

__global__ void k_hist(const int* __restrict__ dst, int* __restrict__ cursor) {
    int e = blockIdx.x * 256 + threadIdx.x;
    if (e < N_EDGES) atomicAdd(&cursor[dst[e]], 1);
}

__global__ void k_scan_bsum(const int* __restrict__ cnt, int* __restrict__ bsum) {
    __shared__ int sd[256];
    int b = blockIdx.x, t = threadIdx.x;
    int base = b * 1024;
    int s = 0;
    for (int i = t; i < 1024; i += 256) {
        int idx = base + i;
        if (idx < N_NODES) s += cnt[idx];
    }
    sd[t] = s; __syncthreads();
    for (int d = 128; d > 0; d >>= 1) {
        if (t < d) sd[t] += sd[t + d];
        __syncthreads();
    }
    if (t == 0) bsum[b] = sd[0];
}

__global__ void k_scan_small(int* __restrict__ bsum, int* __restrict__ offsets) {
    if (threadIdx.x == 0 && blockIdx.x == 0) {
        int run = 0;
        for (int i = 0; i < SCAN_NB; i++) { int v = bsum[i]; bsum[i] = run; run += v; }
        offsets[N_NODES] = run;
    }
}

// cntcur is read as counts, overwritten with start offsets (same index per thread -> safe)
__global__ void k_scan_final(int* __restrict__ cntcur, const int* __restrict__ bsum,
                             int* __restrict__ offsets) {
    __shared__ int ls[256];
    int b = blockIdx.x, t = threadIdx.x;
    int i0 = b * 1024 + t * 4;
    int c0 = 0, c1 = 0, c2 = 0, c3 = 0;
    if (i0 + 0 < N_NODES) c0 = cntcur[i0 + 0];
    if (i0 + 1 < N_NODES) c1 = cntcur[i0 + 1];
    if (i0 + 2 < N_NODES) c2 = cntcur[i0 + 2];
    if (i0 + 3 < N_NODES) c3 = cntcur[i0 + 3];
    int tsum = c0 + c1 + c2 + c3;
    ls[t] = tsum; __syncthreads();
    for (int d = 1; d < 256; d <<= 1) {
        int v = (t >= d) ? ls[t - d] : 0;
        __syncthreads();
        ls[t] += v;
        __syncthreads();
    }
    int tex = ls[t] - tsum;               // exclusive prefix within block
    int base = bsum[b] + tex;
    if (i0 + 0 < N_NODES) { offsets[i0 + 0] = base; cntcur[i0 + 0] = base; base += c0; }
    if (i0 + 1 < N_NODES) { offsets[i0 + 1] = base; cntcur[i0 + 1] = base; base += c1; }
    if (i0 + 2 < N_NODES) { offsets[i0 + 2] = base; cntcur[i0 + 2] = base; base += c2; }
    if (i0 + 3 < N_NODES) { offsets[i0 + 3] = base; cntcur[i0 + 3] = base; base += c3; }
}

__global__ void k_scatter(const int* __restrict__ src, const int* __restrict__ dst,
                          int* __restrict__ cursor, int* __restrict__ ssrc) {
    int e = blockIdx.x * 256 + threadIdx.x;
    if (e >= EN_EDGES) return;
    int s, d;
    if (e < N_EDGES) { s = src[e]; d = dst[e]; }
    else { s = e - N_EDGES; d = s; }
    int pos = atomicAdd(&cursor[d], 1);
    ssrc[pos] = s;
}

// ---------------- Layer 1 GEMM: row-per-lane, scalar W loads ----------------
// Block = 4 waves; tile = 64 rows; wave w computes output cols [16w,16w+16).
__global__ __launch_bounds__(256) void k_gemm1(
        const float* __restrict__ x, const float* __restrict__ W,
        const float* __restrict__ a_s, const float* __restrict__ a_d,
        float* __restrict__ h, float* __restrict__ asn, float* __restrict__ adn) {
    __shared__ float Xs[64 * 129];     // +1 pad: bank = (lane + k) % 32, conflict-free
    __shared__ float asb[4][64], adb[4][64];
    int t = threadIdx.x, lane = t & 63, wave = t >> 6;
    int row0 = blockIdx.x * 64;
    for (int i = t; i < 64 * IN_F; i += 256) {
        int r = i >> 7, c = i & 127;
        Xs[r * 129 + c] = (row0 + r < N_NODES) ? x[(size_t)(row0 + r) * IN_F + c] : 0.f;
    }
    __syncthreads();
    int jb = __builtin_amdgcn_readfirstlane(wave << 4);   // uniform col base -> s_load W
    float acc[16];
    #pragma unroll
    for (int j = 0; j < 16; j++) acc[j] = 0.f;
    for (int k0 = 0; k0 < IN_F; k0 += 8) {
        float xr[8];
        #pragma unroll
        for (int kk = 0; kk < 8; kk++) xr[kk] = Xs[lane * 129 + k0 + kk];
        #pragma unroll
        for (int kk = 0; kk < 8; kk++) {
            const float* wr = W + (k0 + kk) * H_F + jb;
            #pragma unroll
            for (int j = 0; j < 16; j++) acc[j] = fmaf(xr[kk], wr[j], acc[j]);
        }
    }
    int row = row0 + lane;
    float pa = 0.f, pd = 0.f;
    #pragma unroll
    for (int j = 0; j < 16; j++) { pa += acc[j] * a_s[jb + j]; pd += acc[j] * a_d[jb + j]; }
    asb[wave][lane] = pa; adb[wave][lane] = pd;
    if (row < N_NODES) {
        float4* hp = (float4*)(h + (size_t)row * H_F + jb);
        #pragma unroll
        for (int q = 0; q < 4; q++)
            hp[q] = make_float4(acc[4*q], acc[4*q+1], acc[4*q+2], acc[4*q+3]);
    }
    __syncthreads();
    if (wave == 0 && row < N_NODES) {
        asn[row] = asb[0][lane] + asb[1][lane] + asb[2][lane] + asb[3][lane];
        adn[row] = adb[0][lane] + adb[1][lane] + adb[2][lane] + adb[3][lane];
    }
}

// ---------------- Layers 2-5 GEMM: same structure, K=64, fused proj ----------------
__global__ __launch_bounds__(256) void k_gemm(
        const float* __restrict__ xp, const float* __restrict__ W,
        const float* __restrict__ PW, const float* __restrict__ pbias,
        const float* __restrict__ a_s, const float* __restrict__ a_d,
        float* __restrict__ h, float* __restrict__ p,
        float* __restrict__ asn, float* __restrict__ adn) {
    __shared__ float Xs[64 * 65];      // +1 pad, conflict-free
    __shared__ float asb[4][64], adb[4][64];
    int t = threadIdx.x, lane = t & 63, wave = t >> 6;
    int row0 = blockIdx.x * 64;
    for (int i = t; i < 64 * H_F; i += 256) {
        int r = i >> 6, c = i & 63;
        Xs[r * 65 + c] = (row0 + r < N_NODES) ? xp[(size_t)(row0 + r) * H_F + c] : 0.f;
    }
    __syncthreads();
    int jb = __builtin_amdgcn_readfirstlane(wave << 4);
    float acc[16], pac[16];
    #pragma unroll
    for (int j = 0; j < 16; j++) { acc[j] = 0.f; pac[j] = 0.f; }
    for (int k0 = 0; k0 < H_F; k0 += 8) {
        float xr[8];
        #pragma unroll
        for (int kk = 0; kk < 8; kk++) xr[kk] = Xs[lane * 65 + k0 + kk];
        #pragma unroll
        for (int kk = 0; kk < 8; kk++) {
            const float* wr = W  + (k0 + kk) * H_F + jb;
            const float* pr = PW + (k0 + kk) * H_F + jb;
            #pragma unroll
            for (int j = 0; j < 16; j++) {
                acc[j] = fmaf(xr[kk], wr[j], acc[j]);
                pac[j] = fmaf(xr[kk], pr[j], pac[j]);
            }
        }
    }
    int row = row0 + lane;
    float pa = 0.f, pd = 0.f;
    #pragma unroll
    for (int j = 0; j < 16; j++) { pa += acc[j] * a_s[jb + j]; pd += acc[j] * a_d[jb + j]; }
    asb[wave][lane] = pa; adb[wave][lane] = pd;
    if (row < N_NODES) {
        float4* hp = (float4*)(h + (size_t)row * H_F + jb);
        float4* pp = (float4*)(p + (size_t)row * H_F + jb);
        #pragma unroll
        for (int q = 0; q < 4; q++) {
            hp[q] = make_float4(acc[4*q], acc[4*q+1], acc[4*q+2], acc[4*q+3]);
            pp[q] = make_float4(pac[4*q] + pbias[jb+4*q],   pac[4*q+1] + pbias[jb+4*q+1],
                                pac[4*q+2] + pbias[jb+4*q+2], pac[4*q+3] + pbias[jb+4*q+3]);
        }
    }
    __syncthreads();
    if (wave == 0 && row < N_NODES) {
        asn[row] = asb[0][lane] + asb[1][lane] + asb[2][lane] + asb[3][lane];
        adn[row] = adb[0][lane] + adb[1][lane] + adb[2][lane] + adb[3][lane];
    }
}

// ---------------- Attention coefficients: wave per destination ----------------
__global__ __launch_bounds__(256) void k_attn(
        const float* __restrict__ asn, const float* __restrict__ adn,
        const int* __restrict__ offsets, const int* __restrict__ ssrc,
        float* __restrict__ alpha) {
    int t = threadIdx.x, lane = t & 63, wave = t >> 6;
    int d = blockIdx.x * 4 + wave;
    if (d >= N_NODES) return;
    int beg = offsets[d], end = offsets[d + 1];
    float add = adn[d];
    float m = -1e30f, ssum = 0.f;
    for (int j = beg + lane; j < end; j += 64) {
        float e = asn[ssrc[j]] + add;
        e = e < 0.f ? 0.2f * e : e;
        float nm = fmaxf(m, e);
        ssum = ssum * __expf(m - nm) + __expf(e - nm);
        m = nm;
    }
    #pragma unroll
    for (int dlt = 32; dlt > 0; dlt >>= 1) {
        float m2 = __shfl_xor(m, dlt);
        float s2 = __shfl_xor(ssum, dlt);
        float nm = fmaxf(m, m2);
        ssum = ssum * __expf(m - nm) + s2 * __expf(m2 - nm);
        m = nm;
    }
    float inv = 1.f / ssum;   // self-loop guarantees ssum >= 1 post-max
    for (int j = beg + lane; j < end; j += 64) {
        float e = asn[ssrc[j]] + add;
        e = e < 0.f ? 0.2f * e : e;
        alpha[j] = __expf(e - m) * inv;
    }
}

// ---------------- Aggregation: wave per destination, scalar edge metadata ----------------
template <bool HAS_RES>
__global__ __launch_bounds__(256) void k_aggr(
        const float* __restrict__ h, const float* __restrict__ alpha,
        const int* __restrict__ offsets, const int* __restrict__ ssrc,
        const float* __restrict__ bias,
        const float* __restrict__ bg, const float* __restrict__ bb,
        const float* __restrict__ bm, const float* __restrict__ bv,
        const float* __restrict__ res, float* __restrict__ out) {
    int t = threadIdx.x, lane = t & 63, wave = t >> 6;
    int d = blockIdx.x * 4 + wave;
    if (d >= N_NODES) return;
    int du  = __builtin_amdgcn_readfirstlane(d);
    int beg = __builtin_amdgcn_readfirstlane(offsets[du]);
    int end = __builtin_amdgcn_readfirstlane(offsets[du + 1]);
    float acc = 0.f;
    #pragma unroll 4
    for (int e = beg; e < end; ++e) {
        int s   = ssrc[e];      // uniform -> scalar load
        float a = alpha[e];     // uniform -> scalar load
        acc = fmaf(a, h[(size_t)s * H_F + lane], acc);   // coalesced 256B gather
    }
    float v = acc + bias[lane];
    v = fmaxf(v, 0.f);
    v = (v - bm[lane]) * rsqrtf(bv[lane] + BN_EPS) * bg[lane] + bb[lane];
    if (HAS_RES) v += res[(size_t)d * H_F + lane];
    out[(size_t)d * H_F + lane] = v;
}

// ---------------- Mean pool + head ----------------

__global__ __launch_bounds__(256) void k_pool(const float* __restrict__ x, float* __restrict__ pool) {
    __shared__ float sd[256];
    int t = threadIdx.x;
    int lane = t & 63, wave = t >> 6;
    float s = 0.f;
    for (int r = blockIdx.x * 4 + wave; r < N_NODES; r += gridDim.x * 4)
        s += x[(size_t)r * H_F + lane];
    sd[t] = s; __syncthreads();
    if (wave == 0) {
        float v = sd[lane] + sd[64 + lane] + sd[128 + lane] + sd[192 + lane];
        atomicAdd(&pool[lane], v);
    }
}

__global__ void k_head(const float* __restrict__ pool,
                       const float* __restrict__ hW1, const float* __restrict__ hb1,
                       const float* __restrict__ hg, const float* __restrict__ hb,
                       const float* __restrict__ hm, const float* __restrict__ hv,
                       const float* __restrict__ hW2, const float* __restrict__ hb2,
                       float* __restrict__ out) {
    __shared__ float gl[64];
    __shared__ float h1[32];
    int t = threadIdx.x;
    if (t < 64) gl[t] = pool[t] * (1.f / N_NODES);
    __syncthreads();
    if (t < 32) {
        float s = hb1[t];
        for (int l = 0; l < 64; l++) s += gl[l] * hW1[l * 32 + t];
        s = fmaxf(s, 0.f);
        s = (s - hm[t]) * rsqrtf(hv[t] + BN_EPS) * hg[t] + hb[t];
        h1[t] = s;
    }
    __syncthreads();
    if (t == 0) {
        float s = hb2[0];
        for (int j = 0; j < 32; j++) s += h1[j] * hW2[j];
        out[0] = s;
    }
}

// ---------------- Launch ----------------

extern "C" void kernel_launch(void* const* d_in, const int* in_sizes, int n_in,
                              void* d_out, int out_size, void* d_ws, size_t ws_size,
                              hipStream_t stream) {
    (void)in_sizes; (void)n_in; (void)out_size; (void)ws_size;
    const float* x        = (const float*)d_in[0];
    const int*   ei       = (const int*)d_in[1];
    const float* conv1_W  = (const float*)d_in[2];
    const float* conv1_as = (const float*)d_in[3];
    const float* conv1_ad = (const float*)d_in[4];
    const float* conv1_b  = (const float*)d_in[5];
    const float* convW    = (const float*)d_in[6];
    const float* conv_as  = (const float*)d_in[7];
    const float* conv_ad  = (const float*)d_in[8];
    const float* conv_b   = (const float*)d_in[9];
    const float* bn_g     = (const float*)d_in[10];
    const float* bn_b     = (const float*)d_in[11];
    const float* bn_m     = (const float*)d_in[12];
    const float* bn_v     = (const float*)d_in[13];
    const float* projW    = (const float*)d_in[14];
    const float* projb    = (const float*)d_in[15];
    const float* hW1      = (const float*)d_in[16];
    const float* hb1      = (const float*)d_in[17];
    const float* hbn_g    = (const float*)d_in[18];
    const float* hbn_b    = (const float*)d_in[19];
    const float* hbn_m    = (const float*)d_in[20];
    const float* hbn_v    = (const float*)d_in[21];
    const float* hW2      = (const float*)d_in[22];
    const float* hb2      = (const float*)d_in[23];

    const int* e_src = ei;
    const int* e_dst = ei + N_EDGES;

    char* wsb = (char*)d_ws;
    size_t cur = 0;
    auto alloc = [&](size_t bytes) -> void* {
        void* p = wsb + cur;
        cur = (cur + bytes + 255) & ~(size_t)255;
        return p;
    };
    int*   offsets = (int*)alloc((N_NODES + 1) * sizeof(int));
    int*   cursor  = (int*)alloc(N_NODES * sizeof(int));
    int*   ssrc    = (int*)alloc(EN_EDGES * sizeof(int));
    int*   bsum    = (int*)alloc(64 * sizeof(int));
    float* alpha   = (float*)alloc(EN_EDGES * sizeof(float));
    float* h       = (float*)alloc((size_t)N_NODES * H_F * sizeof(float));
    float* p       = (float*)alloc((size_t)N_NODES * H_F * sizeof(float));
    float* asn     = (float*)alloc(N_NODES * sizeof(float));
    float* adn     = (float*)alloc(N_NODES * sizeof(float));
    float* xa      = (float*)alloc((size_t)N_NODES * H_F * sizeof(float));
    float* xb      = (float*)alloc((size_t)N_NODES * H_F * sizeof(float));
    float* pool    = (float*)alloc(64 * sizeof(float));

    // CSR build (graph identical for all layers)
    k_init<<<dim3((N_NODES + 255) / 256), dim3(256), 0, stream>>>(cursor, pool);
    k_hist<<<dim3((N_EDGES + 255) / 256), dim3(256), 0, stream>>>(e_dst, cursor);
    k_scan_bsum<<<dim3(SCAN_NB), dim3(256), 0, stream>>>(cursor, bsum);
    k_scan_small<<<dim3(1), dim3(64), 0, stream>>>(bsum, offsets);
    k_scan_final<<<dim3(SCAN_NB), dim3(256), 0, stream>>>(cursor, bsum, offsets);
    k_scatter<<<dim3((EN_EDGES + 255) / 256), dim3(256), 0, stream>>>(e_src, e_dst, cursor, ssrc);

    dim3 blk(256);
    dim3 gemm_grid((N_NODES + 63) / 64);
    dim3 aggr_grid((N_NODES + 3) / 4);

    // Layer 1
    k_gemm1<<<gemm_grid, blk, 0, stream>>>(x, conv1_W, conv1_as, conv1_ad, h, asn, adn);
    k_attn<<<aggr_grid, blk, 0, stream>>>(asn, adn, offsets, ssrc, alpha);
    k_aggr<false><<<aggr_grid, blk, 0, stream>>>(h, alpha, offsets, ssrc, conv1_b,
                                                 bn_g, bn_b, bn_m, bn_v, nullptr, xa);

    // Layers 2-5
    float* bufs[2] = { xa, xb };
    for (int l = 0; l < 4; l++) {
        float* in  = bufs[l & 1];
        float* out = bufs[(l + 1) & 1];
        k_gemm<<<gemm_grid, blk, 0, stream>>>(in, convW + (size_t)l * H_F * H_F,
                                              projW + (size_t)l * H_F * H_F, projb + l * H_F,
                                              conv_as + l * H_F, conv_ad + l * H_F,
                                              h, p, asn, adn);
        k_attn<<<aggr_grid, blk, 0, stream>>>(asn, adn, offsets, ssrc, alpha);
        k_aggr<true><<<aggr_grid, blk, 0, stream>>>(h, alpha, offsets, ssrc,
                                                    conv_b + l * H_F,
                                                    bn_g + (l + 1) * H_F, bn_b + (l + 1) * H_F,
                                                    bn_m + (l + 1) * H_F, bn_v + (l + 1) * H_F,
                                                    p, out);
    }

    // Pool + head (after 4 residual layers the final activations are in xa)
    k_pool<<<dim3(64), blk, 0, stream>>>(xa, pool);
    k_head<<<dim3(1), dim3(64), 0, stream>>>(pool, hW1, hb1, hbn_g, hbn_b, hbn_m, hbn_v,
                                             hW2, hb2, (float*)d_out);
}

// Round 5
// 566.984 us; speedup vs baseline: 1.6250x; 1.1460x over previous
//
#include <hip/hip_runtime.h>
#include <hip/hip_bf16.h>

#define N_NODES 50000
#define N_EDGES 800000
#define EN_EDGES (N_EDGES + N_NODES)   // with self-loops
#define IN_F 128
#define H_F 64
#define BN_EPS 1e-5f
#define SCAN_NB 49                     // ceil(50000/1024)
#define POOL_NB 256                    // k_pool blocks (partials reduced in k_head)

// ---------------- CSR build ----------------

__global__ void k_init(int* __restrict__ cursor) {
    int i = blockIdx.x * 256 + threadIdx.x;
    if (i < N_NODES) cursor[i] = 1;        // self-loop pre-count
}

__global__ void k_hist(const int* __restrict__ dst, int* __restrict__ cursor) {
    int e = blockIdx.x * 256 + threadIdx.x;
    if (e < N_EDGES) atomicAdd(&cursor[dst[e]], 1);
}

__global__ void k_scan_bsum(const int* __restrict__ cnt, int* __restrict__ bsum) {
    __shared__ int sd[256];
    int b = blockIdx.x, t = threadIdx.x;
    int base = b * 1024;
    int s = 0;
    for (int i = t; i < 1024; i += 256) {
        int idx = base + i;
        if (idx < N_NODES) s += cnt[idx];
    }
    sd[t] = s; __syncthreads();
    for (int d = 128; d > 0; d >>= 1) {
        if (t < d) sd[t] += sd[t + d];
        __syncthreads();
    }
    if (t == 0) bsum[b] = sd[0];
}

__global__ void k_scan_small(int* __restrict__ bsum, int* __restrict__ offsets) {
    if (threadIdx.x == 0 && blockIdx.x == 0) {
        int run = 0;
        for (int i = 0; i < SCAN_NB; i++) { int v = bsum[i]; bsum[i] = run; run += v; }
        offsets[N_NODES] = run;
    }
}

// cntcur is read as counts, overwritten with start offsets (same index per thread -> safe)
__global__ void k_scan_final(int* __restrict__ cntcur, const int* __restrict__ bsum,
                             int* __restrict__ offsets) {
    __shared__ int ls[256];
    int b = blockIdx.x, t = threadIdx.x;
    int i0 = b * 1024 + t * 4;
    int c0 = 0, c1 = 0, c2 = 0, c3 = 0;
    if (i0 + 0 < N_NODES) c0 = cntcur[i0 + 0];
    if (i0 + 1 < N_NODES) c1 = cntcur[i0 + 1];
    if (i0 + 2 < N_NODES) c2 = cntcur[i0 + 2];
    if (i0 + 3 < N_NODES) c3 = cntcur[i0 + 3];
    int tsum = c0 + c1 + c2 + c3;
    ls[t] = tsum; __syncthreads();
    for (int d = 1; d < 256; d <<= 1) {
        int v = (t >= d) ? ls[t - d] : 0;
        __syncthreads();
        ls[t] += v;
        __syncthreads();
    }
    int tex = ls[t] - tsum;               // exclusive prefix within block
    int base = bsum[b] + tex;
    if (i0 + 0 < N_NODES) { offsets[i0 + 0] = base; cntcur[i0 + 0] = base; base += c0; }
    if (i0 + 1 < N_NODES) { offsets[i0 + 1] = base; cntcur[i0 + 1] = base; base += c1; }
    if (i0 + 2 < N_NODES) { offsets[i0 + 2] = base; cntcur[i0 + 2] = base; base += c2; }
    if (i0 + 3 < N_NODES) { offsets[i0 + 3] = base; cntcur[i0 + 3] = base; base += c3; }
}

__global__ void k_scatter(const int* __restrict__ src, const int* __restrict__ dst,
                          int* __restrict__ cursor, int* __restrict__ ssrc) {
    int e = blockIdx.x * 256 + threadIdx.x;
    if (e >= EN_EDGES) return;
    int s, d;
    if (e < N_EDGES) { s = src[e]; d = dst[e]; }
    else { s = e - N_EDGES; d = s; }
    int pos = atomicAdd(&cursor[d], 1);
    ssrc[pos] = s;
}

// ---------------- Layer 1 GEMM: row-per-lane, scalar W loads ----------------
// Block = 4 waves; tile = 64 rows; wave w computes output cols [16w,16w+16).
__global__ __launch_bounds__(256) void k_gemm1(
        const float* __restrict__ x, const float* __restrict__ W,
        const float* __restrict__ a_s, const float* __restrict__ a_d,
        float* __restrict__ h, float* __restrict__ asn, float* __restrict__ adn) {
    __shared__ float Xs[64 * 129];     // +1 pad: bank = (lane + k) % 32, conflict-free
    __shared__ float asb[4][64], adb[4][64];
    int t = threadIdx.x, lane = t & 63, wave = t >> 6;
    int row0 = blockIdx.x * 64;
    for (int i = t; i < 64 * IN_F; i += 256) {
        int r = i >> 7, c = i & 127;
        Xs[r * 129 + c] = (row0 + r < N_NODES) ? x[(size_t)(row0 + r) * IN_F + c] : 0.f;
    }
    __syncthreads();
    int jb = __builtin_amdgcn_readfirstlane(wave << 4);   // uniform col base -> s_load W
    float acc[16];
    #pragma unroll
    for (int j = 0; j < 16; j++) acc[j] = 0.f;
    for (int k0 = 0; k0 < IN_F; k0 += 8) {
        float xr[8];
        #pragma unroll
        for (int kk = 0; kk < 8; kk++) xr[kk] = Xs[lane * 129 + k0 + kk];
        #pragma unroll
        for (int kk = 0; kk < 8; kk++) {
            const float* wr = W + (k0 + kk) * H_F + jb;
            #pragma unroll
            for (int j = 0; j < 16; j++) acc[j] = fmaf(xr[kk], wr[j], acc[j]);
        }
    }
    int row = row0 + lane;
    float pa = 0.f, pd = 0.f;
    #pragma unroll
    for (int j = 0; j < 16; j++) { pa += acc[j] * a_s[jb + j]; pd += acc[j] * a_d[jb + j]; }
    asb[wave][lane] = pa; adb[wave][lane] = pd;
    if (row < N_NODES) {
        float4* hp = (float4*)(h + (size_t)row * H_F + jb);
        #pragma unroll
        for (int q = 0; q < 4; q++)
            hp[q] = make_float4(acc[4*q], acc[4*q+1], acc[4*q+2], acc[4*q+3]);
    }
    __syncthreads();
    if (wave == 0 && row < N_NODES) {
        asn[row] = asb[0][lane] + asb[1][lane] + asb[2][lane] + asb[3][lane];
        adn[row] = adb[0][lane] + adb[1][lane] + adb[2][lane] + adb[3][lane];
    }
}

// ---------------- Layers 2-5 GEMM: same structure, K=64, fused proj ----------------
__global__ __launch_bounds__(256) void k_gemm(
        const float* __restrict__ xp, const float* __restrict__ W,
        const float* __restrict__ PW, const float* __restrict__ pbias,
        const float* __restrict__ a_s, const float* __restrict__ a_d,
        float* __restrict__ h, float* __restrict__ p,
        float* __restrict__ asn, float* __restrict__ adn) {
    __shared__ float Xs[64 * 65];      // +1 pad, conflict-free
    __shared__ float asb[4][64], adb[4][64];
    int t = threadIdx.x, lane = t & 63, wave = t >> 6;
    int row0 = blockIdx.x * 64;
    for (int i = t; i < 64 * H_F; i += 256) {
        int r = i >> 6, c = i & 63;
        Xs[r * 65 + c] = (row0 + r < N_NODES) ? xp[(size_t)(row0 + r) * H_F + c] : 0.f;
    }
    __syncthreads();
    int jb = __builtin_amdgcn_readfirstlane(wave << 4);
    float acc[16], pac[16];
    #pragma unroll
    for (int j = 0; j < 16; j++) { acc[j] = 0.f; pac[j] = 0.f; }
    for (int k0 = 0; k0 < H_F; k0 += 8) {
        float xr[8];
        #pragma unroll
        for (int kk = 0; kk < 8; kk++) xr[kk] = Xs[lane * 65 + k0 + kk];
        #pragma unroll
        for (int kk = 0; kk < 8; kk++) {
            const float* wr = W  + (k0 + kk) * H_F + jb;
            const float* pr = PW + (k0 + kk) * H_F + jb;
            #pragma unroll
            for (int j = 0; j < 16; j++) {
                acc[j] = fmaf(xr[kk], wr[j], acc[j]);
                pac[j] = fmaf(xr[kk], pr[j], pac[j]);
            }
        }
    }
    int row = row0 + lane;
    float pa = 0.f, pd = 0.f;
    #pragma unroll
    for (int j = 0; j < 16; j++) { pa += acc[j] * a_s[jb + j]; pd += acc[j] * a_d[jb + j]; }
    asb[wave][lane] = pa; adb[wave][lane] = pd;
    if (row < N_NODES) {
        float4* hp = (float4*)(h + (size_t)row * H_F + jb);
        float4* pp = (float4*)(p + (size_t)row * H_F + jb);
        #pragma unroll
        for (int q = 0; q < 4; q++) {
            hp[q] = make_float4(acc[4*q], acc[4*q+1], acc[4*q+2], acc[4*q+3]);
            pp[q] = make_float4(pac[4*q] + pbias[jb+4*q],   pac[4*q+1] + pbias[jb+4*q+1],
                                pac[4*q+2] + pbias[jb+4*q+2], pac[4*q+3] + pbias[jb+4*q+3]);
        }
    }
    __syncthreads();
    if (wave == 0 && row < N_NODES) {
        asn[row] = asb[0][lane] + asb[1][lane] + asb[2][lane] + asb[3][lane];
        adn[row] = adb[0][lane] + adb[1][lane] + adb[2][lane] + adb[3][lane];
    }
}

// ---------------- Fused attention softmax + aggregation: wave per destination ----------------
// Pass 1: online softmax over incoming edges (lane-strided). Pass 2: uniform
// serial edge loop; alpha recomputed from scalar loads; lane l gathers feat l.
template <bool HAS_RES>
__global__ __launch_bounds__(256) void k_attn_aggr(
        const float* __restrict__ h, const float* __restrict__ asn, const float* __restrict__ adn,
        const int* __restrict__ offsets, const int* __restrict__ ssrc,
        const float* __restrict__ bias,
        const float* __restrict__ bg, const float* __restrict__ bb,
        const float* __restrict__ bm, const float* __restrict__ bv,
        const float* __restrict__ res, float* __restrict__ out) {
    int t = threadIdx.x, lane = t & 63, wave = t >> 6;
    int d = blockIdx.x * 4 + wave;
    if (d >= N_NODES) return;
    int du  = __builtin_amdgcn_readfirstlane(d);
    int beg = __builtin_amdgcn_readfirstlane(offsets[du]);
    int end = __builtin_amdgcn_readfirstlane(offsets[du + 1]);
    float add = adn[du];

    // pass 1: online softmax stats
    float m = -1e30f, ssum = 0.f;
    for (int j = beg + lane; j < end; j += 64) {
        float e = asn[ssrc[j]] + add;
        e = e < 0.f ? 0.2f * e : e;
        float nm = fmaxf(m, e);
        ssum = ssum * __expf(m - nm) + __expf(e - nm);
        m = nm;
    }
    #pragma unroll
    for (int dlt = 32; dlt > 0; dlt >>= 1) {
        float m2 = __shfl_xor(m, dlt);
        float s2 = __shfl_xor(ssum, dlt);
        float nm = fmaxf(m, m2);
        ssum = ssum * __expf(m - nm) + s2 * __expf(m2 - nm);
        m = nm;
    }
    float inv = 1.f / ssum;   // self-loop guarantees ssum > 0

    // pass 2: weighted gather; edge metadata via wave-uniform scalar loads
    float acc = 0.f;
    #pragma unroll 4
    for (int e = beg; e < end; ++e) {
        int s    = ssrc[e];                    // uniform -> s_load
        float ev = asn[s] + add;               // uniform -> s_load
        ev = ev < 0.f ? 0.2f * ev : ev;
        float a  = __expf(ev - m) * inv;
        acc = fmaf(a, h[(size_t)s * H_F + lane], acc);   // coalesced 256B gather
    }

    float v = acc + bias[lane];
    v = fmaxf(v, 0.f);
    v = (v - bm[lane]) * rsqrtf(bv[lane] + BN_EPS) * bg[lane] + bb[lane];
    if (HAS_RES) v += res[(size_t)d * H_F + lane];
    out[(size_t)d * H_F + lane] = v;
}

// ---------------- Mean pool (partials) + head (final reduce + MLP) ----------------
// Flat float4 sum: thread's feature phase is loop-invariant (stride % 16 == 0).
__global__ __launch_bounds__(256) void k_pool(const float* __restrict__ x,
                                              float* __restrict__ partials) {
    __shared__ float red[256 * 4];
    int t = threadIdx.x, b = blockIdx.x;
    const float4* xv = (const float4*)x;
    const int total = N_NODES * (H_F / 4);          // 800000 float4s
    float a0 = 0.f, a1 = 0.f, a2 = 0.f, a3 = 0.f;
    for (int i = b * 256 + t; i < total; i += POOL_NB * 256) {
        float4 v = xv[i];
        a0 += v.x; a1 += v.y; a2 += v.z; a3 += v.w;
    }
    red[t * 4 + 0] = a0; red[t * 4 + 1] = a1; red[t * 4 + 2] = a2; red[t * 4 + 3] = a3;
    __syncthreads();
    if (t < 64) {
        int p = t >> 2, q = t & 3;                  // feature = p*4 + q = t
        float s = 0.f;
        #pragma unroll
        for (int k = 0; k < 16; k++) s += red[(p + 16 * k) * 4 + q];
        partials[b * H_F + t] = s;
    }
}

__global__ __launch_bounds__(256) void k_head(
        const float* __restrict__ partials,
        const float* __restrict__ hW1, const float* __restrict__ hb1,
        const float* __restrict__ hg, const float* __restrict__ hb,
        const float* __restrict__ hm, const float* __restrict__ hv,
        const float* __restrict__ hW2, const float* __restrict__ hb2,
        float* __restrict__ out) {
    __shared__ float red[256];
    __shared__ float gl[64];
    __shared__ float h1[32];
    int t = threadIdx.x;
    int f = t & 63, g = t >> 6;                     // 4 groups over 256 partial blocks
    float s = 0.f;
    for (int k = g; k < POOL_NB; k += 4) s += partials[k * H_F + f];
    red[t] = s;
    __syncthreads();
    if (t < 64) gl[t] = (red[t] + red[64 + t] + red[128 + t] + red[192 + t]) * (1.f / N_NODES);
    __syncthreads();
    if (t < 32) {
        float v = hb1[t];
        for (int l = 0; l < 64; l++) v += gl[l] * hW1[l * 32 + t];
        v = fmaxf(v, 0.f);
        v = (v - hm[t]) * rsqrtf(hv[t] + BN_EPS) * hg[t] + hb[t];
        h1[t] = v;
    }
    __syncthreads();
    if (t == 0) {
        float v = hb2[0];
        for (int j = 0; j < 32; j++) v += h1[j] * hW2[j];
        out[0] = v;
    }
}

// ---------------- Launch ----------------

extern "C" void kernel_launch(void* const* d_in, const int* in_sizes, int n_in,
                              void* d_out, int out_size, void* d_ws, size_t ws_size,
                              hipStream_t stream) {
    (void)in_sizes; (void)n_in; (void)out_size; (void)ws_size;
    const float* x        = (const float*)d_in[0];
    const int*   ei       = (const int*)d_in[1];
    const float* conv1_W  = (const float*)d_in[2];
    const float* conv1_as = (const float*)d_in[3];
    const float* conv1_ad = (const float*)d_in[4];
    const float* conv1_b  = (const float*)d_in[5];
    const float* convW    = (const float*)d_in[6];
    const float* conv_as  = (const float*)d_in[7];
    const float* conv_ad  = (const float*)d_in[8];
    const float* conv_b   = (const float*)d_in[9];
    const float* bn_g     = (const float*)d_in[10];
    const float* bn_b     = (const float*)d_in[11];
    const float* bn_m     = (const float*)d_in[12];
    const float* bn_v     = (const float*)d_in[13];
    const float* projW    = (const float*)d_in[14];
    const float* projb    = (const float*)d_in[15];
    const float* hW1      = (const float*)d_in[16];
    const float* hb1      = (const float*)d_in[17];
    const float* hbn_g    = (const float*)d_in[18];
    const float* hbn_b    = (const float*)d_in[19];
    const float* hbn_m    = (const float*)d_in[20];
    const float* hbn_v    = (const float*)d_in[21];
    const float* hW2      = (const float*)d_in[22];
    const float* hb2      = (const float*)d_in[23];

    const int* e_src = ei;
    const int* e_dst = ei + N_EDGES;

    char* wsb = (char*)d_ws;
    size_t cur = 0;
    auto alloc = [&](size_t bytes) -> void* {
        void* p = wsb + cur;
        cur = (cur + bytes + 255) & ~(size_t)255;
        return p;
    };
    int*   offsets  = (int*)alloc((N_NODES + 1) * sizeof(int));
    int*   cursor   = (int*)alloc(N_NODES * sizeof(int));
    int*   ssrc     = (int*)alloc(EN_EDGES * sizeof(int));
    int*   bsum     = (int*)alloc(64 * sizeof(int));
    float* h        = (float*)alloc((size_t)N_NODES * H_F * sizeof(float));
    float* p        = (float*)alloc((size_t)N_NODES * H_F * sizeof(float));
    float* asn      = (float*)alloc(N_NODES * sizeof(float));
    float* adn      = (float*)alloc(N_NODES * sizeof(float));
    float* xa       = (float*)alloc((size_t)N_NODES * H_F * sizeof(float));
    float* xb       = (float*)alloc((size_t)N_NODES * H_F * sizeof(float));
    float* partials = (float*)alloc(POOL_NB * H_F * sizeof(float));

    // CSR build (graph identical for all layers)
    k_init<<<dim3((N_NODES + 255) / 256), dim3(256), 0, stream>>>(cursor);
    k_hist<<<dim3((N_EDGES + 255) / 256), dim3(256), 0, stream>>>(e_dst, cursor);
    k_scan_bsum<<<dim3(SCAN_NB), dim3(256), 0, stream>>>(cursor, bsum);
    k_scan_small<<<dim3(1), dim3(64), 0, stream>>>(bsum, offsets);
    k_scan_final<<<dim3(SCAN_NB), dim3(256), 0, stream>>>(cursor, bsum, offsets);
    k_scatter<<<dim3((EN_EDGES + 255) / 256), dim3(256), 0, stream>>>(e_src, e_dst, cursor, ssrc);

    dim3 blk(256);
    dim3 gemm_grid((N_NODES + 63) / 64);
    dim3 aggr_grid((N_NODES + 3) / 4);

    // Layer 1
    k_gemm1<<<gemm_grid, blk, 0, stream>>>(x, conv1_W, conv1_as, conv1_ad, h, asn, adn);
    k_attn_aggr<false><<<aggr_grid, blk, 0, stream>>>(h, asn, adn, offsets, ssrc, conv1_b,
                                                      bn_g, bn_b, bn_m, bn_v, nullptr, xa);

    // Layers 2-5
    float* bufs[2] = { xa, xb };
    for (int l = 0; l < 4; l++) {
        float* in  = bufs[l & 1];
        float* out = bufs[(l + 1) & 1];
        k_gemm<<<gemm_grid, blk, 0, stream>>>(in, convW + (size_t)l * H_F * H_F,
                                              projW + (size_t)l * H_F * H_F, projb + l * H_F,
                                              conv_as + l * H_F, conv_ad + l * H_F,
                                              h, p, asn, adn);
        k_attn_aggr<true><<<aggr_grid, blk, 0, stream>>>(h, asn, adn, offsets, ssrc,
                                                         conv_b + l * H_F,
                                                         bn_g + (l + 1) * H_F, bn_b + (l + 1) * H_F,
                                                         bn_m + (l + 1) * H_F, bn_v + (l + 1) * H_F,
                                                         p, out);
    }

    // Pool + head (after 4 residual layers the final activations are in xa)
    k_pool<<<dim3(POOL_NB), blk, 0, stream>>>(xa, partials);
    k_head<<<dim3(1), blk, 0, stream>>>(partials, hW1, hb1, hbn_g, hbn_b, hbn_m, hbn_v,
                                        hW2, hb2, (float*)d_out);
}